// Round 1
// baseline (666.883 us; speedup 1.0000x reference)
//
#include <hip/hip_runtime.h>
#include <cstdint>
#include <cstddef>

#define RADIX 258
#define EMPTY_ENTRY 0xFFFFFFFFFFFFFFFFULL

// Insert each input coord's packed key -> row index into an open-addressing
// hash table. Keys are unique (coords come from np.unique), so no duplicate
// handling is needed.
__global__ __launch_bounds__(256) void build_hash_kernel(
    const int* __restrict__ coords, int N,
    unsigned long long* __restrict__ tab, unsigned tmask, int tshift)
{
    int i = blockIdx.x * blockDim.x + threadIdx.x;
    if (i >= N) return;
    int x = coords[i * 4 + 0];
    int y = coords[i * 4 + 1];
    int z = coords[i * 4 + 2];
    int b = coords[i * 4 + 3];
    unsigned key = ((unsigned)(b * RADIX + x + 1) * RADIX + (unsigned)(y + 1)) * RADIX
                   + (unsigned)(z + 1);
    unsigned long long entry = ((unsigned long long)key << 32) | (unsigned)i;
    unsigned slot = (key * 2654435761u) >> tshift;
    while (true) {
        unsigned long long prev = atomicCAS(&tab[slot], EMPTY_ENTRY, entry);
        if (prev == EMPTY_ENTRY) break;
        slot = (slot + 1) & tmask;
    }
}

// One 64-lane wave per output row. Lanes 0..26 each look up one kernel-offset
// key; hits are shared via ballot+shuffle; all 64 lanes then gather the
// matching feature rows (lane == channel) and take the running max.
__global__ __launch_bounds__(256) void pool_kernel(
    const float* __restrict__ feats,
    const int* __restrict__ down, int M,
    const unsigned long long* __restrict__ tab, unsigned tmask, int tshift,
    float* __restrict__ out)
{
    int wave = (int)((blockIdx.x * blockDim.x + threadIdx.x) >> 6);
    int lane = threadIdx.x & 63;
    if (wave >= M) return;

    const int* dc = down + (size_t)wave * 4;
    int dx = dc[0], dy = dc[1], dz = dc[2], db = dc[3];
    unsigned base = ((unsigned)(db * RADIX + dx + 1) * RADIX + (unsigned)(dy + 1)) * RADIX
                    + (unsigned)(dz + 1);

    int src = -1;
    if (lane < 27) {
        int ox = lane % 3 - 1;
        int oy = (lane / 3) % 3 - 1;
        int oz = lane / 9 - 1;
        int delta = ox * (RADIX * RADIX) + oy * RADIX + oz;
        unsigned key = (unsigned)((int)base + delta);
        unsigned slot = (key * 2654435761u) >> tshift;
        while (true) {
            unsigned long long e = tab[slot];
            if (e == EMPTY_ENTRY) break;                 // miss
            if ((unsigned)(e >> 32) == key) {            // hit
                src = (int)(unsigned)e;
                break;
            }
            slot = (slot + 1) & tmask;
        }
    }

    unsigned long long mask = __ballot(src >= 0);
    float acc = -INFINITY;
    while (mask) {
        int bit = __ffsll(mask) - 1;
        int s = __shfl(src, bit);
        acc = fmaxf(acc, feats[(size_t)s * 64 + lane]);
        mask &= mask - 1;
    }
    out[(size_t)wave * 64 + lane] = isinf(acc) ? 0.0f : acc;
}

extern "C" void kernel_launch(void* const* d_in, const int* in_sizes, int n_in,
                              void* d_out, int out_size, void* d_ws, size_t ws_size,
                              hipStream_t stream)
{
    const float* feats  = (const float*)d_in[0];
    const int*   coords = (const int*)d_in[1];
    const int*   down   = (const int*)d_in[2];
    float*       out    = (float*)d_out;

    int N = in_sizes[1] / 4;
    int M = in_sizes[2] / 4;

    // Pick hash-table size: prefer 2^22 entries (33.5 MB, ~28% load), shrink
    // if the workspace is smaller.
    int logT = 22;
    while (logT > 19 && ((size_t)8u << logT) > ws_size) logT--;
    unsigned T = 1u << logT;
    unsigned tmask = T - 1u;
    int tshift = 32 - logT;

    unsigned long long* tab = (unsigned long long*)d_ws;
    hipMemsetAsync(tab, 0xFF, (size_t)T * 8, stream);

    int blkA = 256;
    int grdA = (N + blkA - 1) / blkA;
    build_hash_kernel<<<grdA, blkA, 0, stream>>>(coords, N, tab, tmask, tshift);

    int wavesPerBlk = 4;                       // 256 threads = 4 waves
    int grdB = (M + wavesPerBlk - 1) / wavesPerBlk;
    pool_kernel<<<grdB, 256, 0, stream>>>(feats, down, M, tab, tmask, tshift, out);
}

// Round 2
// 422.805 us; speedup vs baseline: 1.5773x; 1.5773x over previous
//
#include <hip/hip_runtime.h>
#include <cstdint>
#include <cstddef>

#define RADIX 258
#define EMPTY_ENTRY 0xFFFFFFFFFFFFFFFFULL
#define MAP_DIM 128                 // down coords are even, 0..254 -> /2 in 0..127
#define MAP_SLOTS (2 * MAP_DIM * MAP_DIM * MAP_DIM)   // batch * 128^3 = 4.19M

// ---------------------------------------------------------------------------
// FAST PATH: dense parent map + compact neighbor lists + parallel gather
// ---------------------------------------------------------------------------

// map[(b*128 + x/2)*128 + y/2)*128 + z/2] = down-row index
__global__ __launch_bounds__(256) void build_map_kernel(
    const int* __restrict__ down, int M, unsigned* __restrict__ map)
{
    int j = blockIdx.x * blockDim.x + threadIdx.x;
    if (j >= M) return;
    const int4 c = ((const int4*)down)[j];
    unsigned idx = (((unsigned)(c.w * MAP_DIM + (c.x >> 1)) * MAP_DIM)
                    + (unsigned)(c.y >> 1)) * MAP_DIM + (unsigned)(c.z >> 1);
    map[idx] = (unsigned)j;
}

// For each input voxel p: its candidate parents q satisfy q = p - off,
// off in {-1,0,1}^3, q even per axis. Even axis -> q=p; odd axis -> q=p-1,p+1.
// Look each up in the dense map; on hit, append input row i to out-row qi's
// compact list. (atomicAdd order varies, but max over the set is invariant.)
__global__ __launch_bounds__(256) void scatter_kernel(
    const int* __restrict__ coords, int N,
    const unsigned* __restrict__ map,
    unsigned* __restrict__ cnt, unsigned* __restrict__ nbmap)
{
    int i = blockIdx.x * blockDim.x + threadIdx.x;
    if (i >= N) return;
    const int4 c = ((const int4*)coords)[i];
    int qx[2], qy[2], qz[2];
    int nx = 1, ny = 1, nz = 1;
    if (c.x & 1) { qx[0] = (c.x - 1) >> 1; if (c.x + 1 <= 254) qx[nx++] = (c.x + 1) >> 1; }
    else         { qx[0] = c.x >> 1; }
    if (c.y & 1) { qy[0] = (c.y - 1) >> 1; if (c.y + 1 <= 254) qy[ny++] = (c.y + 1) >> 1; }
    else         { qy[0] = c.y >> 1; }
    if (c.z & 1) { qz[0] = (c.z - 1) >> 1; if (c.z + 1 <= 254) qz[nz++] = (c.z + 1) >> 1; }
    else         { qz[0] = c.z >> 1; }
    unsigned bbase = (unsigned)(c.w * MAP_DIM);
    for (int ix = 0; ix < nx; ++ix) {
        unsigned xb = (bbase + (unsigned)qx[ix]) * MAP_DIM;
        for (int iy = 0; iy < ny; ++iy) {
            unsigned yb = (xb + (unsigned)qy[iy]) * MAP_DIM;
            for (int iz = 0; iz < nz; ++iz) {
                unsigned qi = map[yb + (unsigned)qz[iz]];
                if (qi != 0xFFFFFFFFu) {
                    unsigned pos = atomicAdd(&cnt[qi], 1u);
                    nbmap[(size_t)qi * 27 + pos] = (unsigned)i;
                }
            }
        }
    }
}

// One wave per output row. Lanes 0..26 load the row's neighbor indices.
// The wave is split into 4 groups of 16 lanes; group g processes hit slot
// r+g each round with float4 loads (16 lanes x 16B = full 256B row), so up
// to 4 feature rows are in flight simultaneously. Cross-group shuffle-max,
// group 0 writes the row.
__global__ __launch_bounds__(256) void gather_kernel(
    const float* __restrict__ feats,
    const unsigned* __restrict__ cnt,
    const unsigned* __restrict__ nbmap,
    float* __restrict__ out, int M)
{
    int wave = (int)((blockIdx.x * blockDim.x + threadIdx.x) >> 6);
    int lane = threadIdx.x & 63;
    if (wave >= M) return;

    int c = (int)cnt[wave];
    int idx = -1;
    if (lane < 27 && lane < c) idx = (int)nbmap[(size_t)wave * 27 + lane];

    int g  = lane >> 4;     // hit-slot group 0..3
    int ch = lane & 15;     // channel quad (4 floats)

    float4 acc = make_float4(-INFINITY, -INFINITY, -INFINITY, -INFINITY);
    for (int r = 0; r < c; r += 4) {
        int h = r + g;
        int s = __shfl(idx, h);
        if (h < c) {
            float4 v = ((const float4*)feats)[(size_t)s * 16 + ch];
            acc.x = fmaxf(acc.x, v.x);
            acc.y = fmaxf(acc.y, v.y);
            acc.z = fmaxf(acc.z, v.z);
            acc.w = fmaxf(acc.w, v.w);
        }
    }
    // reduce the 4 group partials (lanes with equal ch hold the same channels)
    for (int d = 16; d < 64; d <<= 1) {
        acc.x = fmaxf(acc.x, __shfl_xor(acc.x, d));
        acc.y = fmaxf(acc.y, __shfl_xor(acc.y, d));
        acc.z = fmaxf(acc.z, __shfl_xor(acc.z, d));
        acc.w = fmaxf(acc.w, __shfl_xor(acc.w, d));
    }
    if (g == 0) {
        if (c == 0) acc = make_float4(0.f, 0.f, 0.f, 0.f);  // cannot happen; defensive
        ((float4*)out)[(size_t)wave * 16 + ch] = acc;
    }
}

// ---------------------------------------------------------------------------
// FALLBACK PATH (round-1 proven kernel) if ws is too small for the nbmap
// ---------------------------------------------------------------------------

__global__ __launch_bounds__(256) void build_hash_kernel(
    const int* __restrict__ coords, int N,
    unsigned long long* __restrict__ tab, unsigned tmask, int tshift)
{
    int i = blockIdx.x * blockDim.x + threadIdx.x;
    if (i >= N) return;
    int x = coords[i * 4 + 0];
    int y = coords[i * 4 + 1];
    int z = coords[i * 4 + 2];
    int b = coords[i * 4 + 3];
    unsigned key = ((unsigned)(b * RADIX + x + 1) * RADIX + (unsigned)(y + 1)) * RADIX
                   + (unsigned)(z + 1);
    unsigned long long entry = ((unsigned long long)key << 32) | (unsigned)i;
    unsigned slot = (key * 2654435761u) >> tshift;
    while (true) {
        unsigned long long prev = atomicCAS(&tab[slot], EMPTY_ENTRY, entry);
        if (prev == EMPTY_ENTRY) break;
        slot = (slot + 1) & tmask;
    }
}

__global__ __launch_bounds__(256) void pool_kernel(
    const float* __restrict__ feats,
    const int* __restrict__ down, int M,
    const unsigned long long* __restrict__ tab, unsigned tmask, int tshift,
    float* __restrict__ out)
{
    int wave = (int)((blockIdx.x * blockDim.x + threadIdx.x) >> 6);
    int lane = threadIdx.x & 63;
    if (wave >= M) return;

    const int* dc = down + (size_t)wave * 4;
    int dx = dc[0], dy = dc[1], dz = dc[2], db = dc[3];
    unsigned base = ((unsigned)(db * RADIX + dx + 1) * RADIX + (unsigned)(dy + 1)) * RADIX
                    + (unsigned)(dz + 1);

    int src = -1;
    if (lane < 27) {
        int ox = lane % 3 - 1;
        int oy = (lane / 3) % 3 - 1;
        int oz = lane / 9 - 1;
        int delta = ox * (RADIX * RADIX) + oy * RADIX + oz;
        unsigned key = (unsigned)((int)base + delta);
        unsigned slot = (key * 2654435761u) >> tshift;
        while (true) {
            unsigned long long e = tab[slot];
            if (e == EMPTY_ENTRY) break;
            if ((unsigned)(e >> 32) == key) { src = (int)(unsigned)e; break; }
            slot = (slot + 1) & tmask;
        }
    }
    unsigned long long mask = __ballot(src >= 0);
    float acc = -INFINITY;
    while (mask) {
        int bit = __ffsll(mask) - 1;
        int s = __shfl(src, bit);
        acc = fmaxf(acc, feats[(size_t)s * 64 + lane]);
        mask &= mask - 1;
    }
    out[(size_t)wave * 64 + lane] = isinf(acc) ? 0.0f : acc;
}

// ---------------------------------------------------------------------------

extern "C" void kernel_launch(void* const* d_in, const int* in_sizes, int n_in,
                              void* d_out, int out_size, void* d_ws, size_t ws_size,
                              hipStream_t stream)
{
    const float* feats  = (const float*)d_in[0];
    const int*   coords = (const int*)d_in[1];
    const int*   down   = (const int*)d_in[2];
    float*       out    = (float*)d_out;

    int N = in_sizes[1] / 4;
    int M = in_sizes[2] / 4;

    size_t map_bytes = (size_t)MAP_SLOTS * 4;          // 16.8 MB
    size_t cnt_bytes = (size_t)M * 4;
    size_t nb_bytes  = (size_t)M * 27 * 4;
    size_t need = map_bytes + cnt_bytes + nb_bytes;    // ~117 MB

    if (ws_size >= need) {
        unsigned* map   = (unsigned*)d_ws;
        unsigned* cnt   = (unsigned*)((char*)d_ws + map_bytes);
        unsigned* nbmap = (unsigned*)((char*)d_ws + map_bytes + cnt_bytes);

        hipMemsetAsync(map, 0xFF, map_bytes, stream);
        hipMemsetAsync(cnt, 0x00, cnt_bytes, stream);

        build_map_kernel<<<(M + 255) / 256, 256, 0, stream>>>(down, M, map);
        scatter_kernel<<<(N + 255) / 256, 256, 0, stream>>>(coords, N, map, cnt, nbmap);
        gather_kernel<<<(M + 3) / 4, 256, 0, stream>>>(feats, cnt, nbmap, out, M);
    } else {
        // fallback: round-1 hash-probe kernel (needs only the hash table)
        int logT = 22;
        while (logT > 19 && ((size_t)8u << logT) > ws_size) logT--;
        unsigned T = 1u << logT;
        unsigned tmask = T - 1u;
        int tshift = 32 - logT;
        unsigned long long* tab = (unsigned long long*)d_ws;
        hipMemsetAsync(tab, 0xFF, (size_t)T * 8, stream);
        build_hash_kernel<<<(N + 255) / 256, 256, 0, stream>>>(coords, N, tab, tmask, tshift);
        pool_kernel<<<(M + 63) / 64 * 64 / 256 + 1, 256, 0, stream>>>(
            feats, down, M, tab, tmask, tshift, out);
    }
}

// Round 3
// 208.651 us; speedup vs baseline: 3.1962x; 2.0264x over previous
//
#include <hip/hip_runtime.h>
#include <cstdint>
#include <cstddef>

#define RADIX 258
#define EMPTY_ENTRY 0xFFFFFFFFFFFFFFFFULL
#define MAP_DIM 128                 // down coords are even, 0..254 -> /2 in 0..127
#define MAP_SLOTS (2 * MAP_DIM * MAP_DIM * MAP_DIM)   // batch * 128^3 = 4.19M

typedef float f32x4 __attribute__((ext_vector_type(4)));

// ---------------------------------------------------------------------------
// FAST PATH: dense parent map + compact neighbor lists + 4-row/4-deep gather
// ---------------------------------------------------------------------------

__global__ __launch_bounds__(256) void build_map_kernel(
    const int* __restrict__ down, int M, unsigned* __restrict__ map)
{
    int j = blockIdx.x * blockDim.x + threadIdx.x;
    if (j >= M) return;
    const int4 c = ((const int4*)down)[j];
    unsigned idx = (((unsigned)(c.w * MAP_DIM + (c.x >> 1)) * MAP_DIM)
                    + (unsigned)(c.y >> 1)) * MAP_DIM + (unsigned)(c.z >> 1);
    map[idx] = (unsigned)j;
}

// For each input voxel p: candidate parents q = even-floored neighbors
// (even axis -> 1 candidate, odd axis -> 2). On hit, append row i to the
// parent's compact list (atomic order varies; max over the set is invariant).
__global__ __launch_bounds__(256) void scatter_kernel(
    const int* __restrict__ coords, int N,
    const unsigned* __restrict__ map,
    unsigned* __restrict__ cnt, unsigned* __restrict__ nbmap)
{
    int i = blockIdx.x * blockDim.x + threadIdx.x;
    if (i >= N) return;
    const int4 c = ((const int4*)coords)[i];
    int qx[2], qy[2], qz[2];
    int nx = 1, ny = 1, nz = 1;
    if (c.x & 1) { qx[0] = (c.x - 1) >> 1; if (c.x + 1 <= 254) qx[nx++] = (c.x + 1) >> 1; }
    else         { qx[0] = c.x >> 1; }
    if (c.y & 1) { qy[0] = (c.y - 1) >> 1; if (c.y + 1 <= 254) qy[ny++] = (c.y + 1) >> 1; }
    else         { qy[0] = c.y >> 1; }
    if (c.z & 1) { qz[0] = (c.z - 1) >> 1; if (c.z + 1 <= 254) qz[nz++] = (c.z + 1) >> 1; }
    else         { qz[0] = c.z >> 1; }
    unsigned bbase = (unsigned)(c.w * MAP_DIM);
    for (int ix = 0; ix < nx; ++ix) {
        unsigned xb = (bbase + (unsigned)qx[ix]) * MAP_DIM;
        for (int iy = 0; iy < ny; ++iy) {
            unsigned yb = (xb + (unsigned)qy[iy]) * MAP_DIM;
            for (int iz = 0; iz < nz; ++iz) {
                unsigned qi = map[yb + (unsigned)qz[iz]];
                if (qi != 0xFFFFFFFFu) {
                    unsigned pos = atomicAdd(&cnt[qi], 1u);
                    nbmap[(size_t)qi * 27 + pos] = (unsigned)i;
                }
            }
        }
    }
}

// One wave = 4 output rows (groups of 16 lanes; lane j holds channel quad j).
// Each round issues 4 independent float4 gathers per group (indices clamped
// to c-1: redundant re-max of the same row is idempotent => branch-free).
__global__ __launch_bounds__(256) void gather4_kernel(
    const float* __restrict__ feats,
    const unsigned* __restrict__ cnt,
    const unsigned* __restrict__ nbmap,
    float* __restrict__ out, int M, int nwg)
{
    // bijective XCD-chunked block swizzle (8 XCDs)
    int bid = blockIdx.x;
    int q = nwg >> 3, r = nwg & 7;
    int xcd = bid & 7, orig = bid >> 3;
    int swz = (xcd < r ? xcd * (q + 1) : r * (q + 1) + (xcd - r) * q) + orig;

    int lane = threadIdx.x & 63;
    int g    = lane >> 4;          // row within this wave's quad
    int j    = lane & 15;          // channel quad
    int wave = swz * 4 + (int)(threadIdx.x >> 6);
    int row  = wave * 4 + g;
    bool valid = row < M;

    int c = valid ? (int)cnt[row] : 0;
    const unsigned* nb = nbmap + (size_t)row * 27;
    int idxA = 0;
    if (valid && j < c) idxA = (int)nb[j];

    const f32x4* f4 = (const f32x4*)feats;
    int gb = g << 4;
    f32x4 acc = {-INFINITY, -INFINITY, -INFINITY, -INFINITY};
    for (int r4 = 0; r4 < c; r4 += 4) {
        int cm1 = c - 1;
        int h0 = min(r4,     cm1);
        int h1 = min(r4 + 1, cm1);
        int h2 = min(r4 + 2, cm1);
        int h3 = min(r4 + 3, cm1);
        int a0 = __shfl(idxA, gb + min(h0, 15));
        int a1 = __shfl(idxA, gb + min(h1, 15));
        int a2 = __shfl(idxA, gb + min(h2, 15));
        int a3 = __shfl(idxA, gb + min(h3, 15));
        int s0 = (h0 < 16) ? a0 : (int)nb[h0];   // c>16 is rare; exec-masked load
        int s1 = (h1 < 16) ? a1 : (int)nb[h1];
        int s2 = (h2 < 16) ? a2 : (int)nb[h2];
        int s3 = (h3 < 16) ? a3 : (int)nb[h3];
        f32x4 v0 = f4[(size_t)s0 * 16 + j];
        f32x4 v1 = f4[(size_t)s1 * 16 + j];
        f32x4 v2 = f4[(size_t)s2 * 16 + j];
        f32x4 v3 = f4[(size_t)s3 * 16 + j];
        acc.x = fmaxf(fmaxf(fmaxf(acc.x, v0.x), fmaxf(v1.x, v2.x)), v3.x);
        acc.y = fmaxf(fmaxf(fmaxf(acc.y, v0.y), fmaxf(v1.y, v2.y)), v3.y);
        acc.z = fmaxf(fmaxf(fmaxf(acc.z, v0.z), fmaxf(v1.z, v2.z)), v3.z);
        acc.w = fmaxf(fmaxf(fmaxf(acc.w, v0.w), fmaxf(v1.w, v2.w)), v3.w);
    }
    if (valid) {
        if (c == 0) acc = (f32x4){0.f, 0.f, 0.f, 0.f};   // defensive (no-neighbor row)
        __builtin_nontemporal_store(acc, (f32x4*)out + (size_t)row * 16 + j);
    }
}

// ---------------------------------------------------------------------------
// FALLBACK PATH (round-1 proven kernel) if ws is too small for the nbmap
// ---------------------------------------------------------------------------

__global__ __launch_bounds__(256) void build_hash_kernel(
    const int* __restrict__ coords, int N,
    unsigned long long* __restrict__ tab, unsigned tmask, int tshift)
{
    int i = blockIdx.x * blockDim.x + threadIdx.x;
    if (i >= N) return;
    int x = coords[i * 4 + 0];
    int y = coords[i * 4 + 1];
    int z = coords[i * 4 + 2];
    int b = coords[i * 4 + 3];
    unsigned key = ((unsigned)(b * RADIX + x + 1) * RADIX + (unsigned)(y + 1)) * RADIX
                   + (unsigned)(z + 1);
    unsigned long long entry = ((unsigned long long)key << 32) | (unsigned)i;
    unsigned slot = (key * 2654435761u) >> tshift;
    while (true) {
        unsigned long long prev = atomicCAS(&tab[slot], EMPTY_ENTRY, entry);
        if (prev == EMPTY_ENTRY) break;
        slot = (slot + 1) & tmask;
    }
}

__global__ __launch_bounds__(256) void pool_kernel(
    const float* __restrict__ feats,
    const int* __restrict__ down, int M,
    const unsigned long long* __restrict__ tab, unsigned tmask, int tshift,
    float* __restrict__ out)
{
    int wave = (int)((blockIdx.x * blockDim.x + threadIdx.x) >> 6);
    int lane = threadIdx.x & 63;
    if (wave >= M) return;

    const int* dc = down + (size_t)wave * 4;
    int dx = dc[0], dy = dc[1], dz = dc[2], db = dc[3];
    unsigned base = ((unsigned)(db * RADIX + dx + 1) * RADIX + (unsigned)(dy + 1)) * RADIX
                    + (unsigned)(dz + 1);

    int src = -1;
    if (lane < 27) {
        int ox = lane % 3 - 1;
        int oy = (lane / 3) % 3 - 1;
        int oz = lane / 9 - 1;
        int delta = ox * (RADIX * RADIX) + oy * RADIX + oz;
        unsigned key = (unsigned)((int)base + delta);
        unsigned slot = (key * 2654435761u) >> tshift;
        while (true) {
            unsigned long long e = tab[slot];
            if (e == EMPTY_ENTRY) break;
            if ((unsigned)(e >> 32) == key) { src = (int)(unsigned)e; break; }
            slot = (slot + 1) & tmask;
        }
    }
    unsigned long long mask = __ballot(src >= 0);
    float acc = -INFINITY;
    while (mask) {
        int bit = __ffsll(mask) - 1;
        int s = __shfl(src, bit);
        acc = fmaxf(acc, feats[(size_t)s * 64 + lane]);
        mask &= mask - 1;
    }
    out[(size_t)wave * 64 + lane] = isinf(acc) ? 0.0f : acc;
}

// ---------------------------------------------------------------------------

extern "C" void kernel_launch(void* const* d_in, const int* in_sizes, int n_in,
                              void* d_out, int out_size, void* d_ws, size_t ws_size,
                              hipStream_t stream)
{
    const float* feats  = (const float*)d_in[0];
    const int*   coords = (const int*)d_in[1];
    const int*   down   = (const int*)d_in[2];
    float*       out    = (float*)d_out;

    int N = in_sizes[1] / 4;
    int M = in_sizes[2] / 4;

    size_t map_bytes = (size_t)MAP_SLOTS * 4;          // 16.8 MB
    size_t cnt_bytes = (size_t)M * 4;
    size_t nb_bytes  = (size_t)M * 27 * 4;
    size_t need = map_bytes + cnt_bytes + nb_bytes;    // ~117 MB

    if (ws_size >= need) {
        unsigned* map   = (unsigned*)d_ws;
        unsigned* cnt   = (unsigned*)((char*)d_ws + map_bytes);
        unsigned* nbmap = (unsigned*)((char*)d_ws + map_bytes + cnt_bytes);

        hipMemsetAsync(map, 0xFF, map_bytes, stream);
        hipMemsetAsync(cnt, 0x00, cnt_bytes, stream);

        build_map_kernel<<<(M + 255) / 256, 256, 0, stream>>>(down, M, map);
        scatter_kernel<<<(N + 255) / 256, 256, 0, stream>>>(coords, N, map, cnt, nbmap);

        int nwg = (M + 15) / 16;                       // 16 rows per block
        gather4_kernel<<<nwg, 256, 0, stream>>>(feats, cnt, nbmap, out, M, nwg);
    } else {
        int logT = 22;
        while (logT > 19 && ((size_t)8u << logT) > ws_size) logT--;
        unsigned T = 1u << logT;
        unsigned tmask = T - 1u;
        int tshift = 32 - logT;
        unsigned long long* tab = (unsigned long long*)d_ws;
        hipMemsetAsync(tab, 0xFF, (size_t)T * 8, stream);
        build_hash_kernel<<<(N + 255) / 256, 256, 0, stream>>>(coords, N, tab, tmask, tshift);
        pool_kernel<<<(M * 64 + 255) / 256, 256, 0, stream>>>(
            feats, down, M, tab, tmask, tshift, out);
    }
}